// Round 6
// baseline (435.872 us; speedup 1.0000x reference)
//
#include <hip/hip_runtime.h>
#include <hip/hip_bf16.h>

// FeastNet fused: B=2, V=50000, NB=16, C=64, K=8, O=64
// out[b,v,o] = inv_deg[v] * sum_{c,k} M[c,k] * W[c,k,o]
//   M[c,k]   = sum_n patches[b,v,n,c] * q[b,v,n,k]
//   q        = softmax_k( xu[self] - xu[neighbor] ),  xu = x @ u
// v2: dedup softmax via fp32 qlds (aliased with Mlds), conflict-free M swizzle,
//     explicit patch prefetch ping-pong, merged prep kernel.

constexpr int BB = 2;
constexpr int VV = 50000;
#define NB 16
#define CC 64
#define KK 8
#define OO 64
#define TV 32  // vertices per workgroup

typedef __attribute__((ext_vector_type(8))) short bf16x8;  // 8 bf16 (4 VGPRs)
typedef __attribute__((ext_vector_type(4))) float f32x4;

static __device__ __forceinline__ short f2b(float f) {
    __hip_bfloat16 h = __float2bfloat16(f);  // RNE
    return *reinterpret_cast<short*>(&h);
}

// ---- K0 merged prep: xu (blocks [0,XUB)) + Wb prep (blocks [XUB, XUB+WPB)) ----
constexpr int XUB = (BB * VV * 2 + 255) / 256;  // 2 threads per row -> 782
constexpr int WPB = (CC * KK * OO) / 256;       // 128

__global__ void prep_kernel(const float* __restrict__ x,
                            const float* __restrict__ u,
                            float* __restrict__ xu,
                            const float* __restrict__ W,
                            short* __restrict__ Wb) {
    int blk = blockIdx.x;
    if (blk < XUB) {
        // xu[g,k] = sum_c x[g,c]*u[c,k]; thread = (row g, k-half)
        int t = blk * 256 + threadIdx.x;
        if (t >= BB * VV * 2) return;
        int g = t >> 1, half = t & 1;
        const float4* xr =
            reinterpret_cast<const float4*>(x) + (size_t)g * (CC / 4);
        const float4* u4 = reinterpret_cast<const float4*>(u);
        float a0 = 0.f, a1 = 0.f, a2 = 0.f, a3 = 0.f;
#pragma unroll
        for (int c4 = 0; c4 < CC / 4; ++c4) {
            float4 xv = xr[c4];
            float4 u0 = u4[(c4 * 4 + 0) * 2 + half];
            float4 u1 = u4[(c4 * 4 + 1) * 2 + half];
            float4 u2 = u4[(c4 * 4 + 2) * 2 + half];
            float4 u3 = u4[(c4 * 4 + 3) * 2 + half];
            a0 = fmaf(xv.x, u0.x, a0); a1 = fmaf(xv.x, u0.y, a1);
            a2 = fmaf(xv.x, u0.z, a2); a3 = fmaf(xv.x, u0.w, a3);
            a0 = fmaf(xv.y, u1.x, a0); a1 = fmaf(xv.y, u1.y, a1);
            a2 = fmaf(xv.y, u1.z, a2); a3 = fmaf(xv.y, u1.w, a3);
            a0 = fmaf(xv.z, u2.x, a0); a1 = fmaf(xv.z, u2.y, a1);
            a2 = fmaf(xv.z, u2.z, a2); a3 = fmaf(xv.z, u2.w, a3);
            a0 = fmaf(xv.w, u3.x, a0); a1 = fmaf(xv.w, u3.y, a1);
            a2 = fmaf(xv.w, u3.z, a2); a3 = fmaf(xv.w, u3.w, a3);
        }
        reinterpret_cast<float4*>(xu)[(size_t)g * 2 + half] =
            make_float4(a0, a1, a2, a3);
    } else {
        // W (C,K*O) f32 -> Wb bf16 in MFMA B-fragment order.
        // Wb[((ks*4+gct)*64+l)*8+e] = W[(ks*32+(l>>4)*8+e)*OO + gct*16+(l&15)]
        int dst = (blk - XUB) * 256 + threadIdx.x;
        int e = dst & 7;
        int l = (dst >> 3) & 63;
        int ctk = dst >> 9;
        int gct = ctk & 3;
        int ks = ctk >> 2;
        int ck = ks * 32 + (l >> 4) * 8 + e;
        int o = gct * 16 + (l & 15);
        Wb[dst] = f2b(W[ck * OO + o]);
    }
}

// ---------------- K2: fused q + M-build + MFMA contraction ----------------
__global__ __launch_bounds__(256, 4) void feast_fused(
    const float* __restrict__ x, const int* __restrict__ adj,
    const float* __restrict__ xu, const short* __restrict__ Wb,
    float* __restrict__ out) {
    // 32KB: first holds qlds fp32 [n][vl][k] (16KB), then reused as Mlds
    __shared__ char smem[TV * 1024];
    __shared__ float sInvd[TV];

    int t = threadIdx.x;
    int b = blockIdx.y;
    int v0 = blockIdx.x * TV;
    int vl = t >> 3;  // vertex local 0..31
    int j = t & 7;    // channel-octet 0..7
    int v = v0 + vl;
    if (v >= VV) v = VV - 1;

    float* qlds = reinterpret_cast<float*>(smem);

    // ---- adj row (kept in regs, compile-time indexed only) ----
    int a[NB];
    const int4* arow = reinterpret_cast<const int4*>(adj + (size_t)v * NB);
#pragma unroll
    for (int n4 = 0; n4 < 4; ++n4) {
        int4 t4 = arow[n4];
        a[n4 * 4 + 0] = t4.x;
        a[n4 * 4 + 1] = t4.y;
        a[n4 * 4 + 2] = t4.z;
        a[n4 * 4 + 3] = t4.w;
    }
    float deg = 0.f;
#pragma unroll
    for (int n = 0; n < NB; ++n) deg += (a[n] != 0) ? 1.f : 0.f;
    if (j == 0) sInvd[vl] = (deg > 0.f) ? (1.f / deg) : 0.f;

    const float4* xu4 = reinterpret_cast<const float4*>(xu);
    const float4* x4 = reinterpret_cast<const float4*>(x);

    // ---- Phase A: softmax q for this thread's 2 neighbors -> qlds ----
    {
        int gs = b * VV + v;
        float4 s0 = xu4[(size_t)gs * 2], s1 = xu4[(size_t)gs * 2 + 1];
        float xs[KK] = {s0.x, s0.y, s0.z, s0.w, s1.x, s1.y, s1.z, s1.w};
        int2 ap = *reinterpret_cast<const int2*>(adj + (size_t)v * NB + 2 * j);

        auto qbuild = [&](int an, int nn) {
            int g = b * VV + (an ? an - 1 : 0);
            float4 n0 = xu4[(size_t)g * 2], n1 = xu4[(size_t)g * 2 + 1];
            float l8[KK] = {xs[0] - n0.x, xs[1] - n0.y, xs[2] - n0.z,
                            xs[3] - n0.w, xs[4] - n1.x, xs[5] - n1.y,
                            xs[6] - n1.z, xs[7] - n1.w};
            float mx = l8[0];
#pragma unroll
            for (int k = 1; k < KK; ++k) mx = fmaxf(mx, l8[k]);
            float e8[KK];
            float sum = 0.f;
#pragma unroll
            for (int k = 0; k < KK; ++k) {
                e8[k] = __expf(l8[k] - mx);
                sum += e8[k];
            }
            float r = an ? (1.f / sum) : 0.f;
            f32x4 q0 = {e8[0] * r, e8[1] * r, e8[2] * r, e8[3] * r};
            f32x4 q1 = {e8[4] * r, e8[5] * r, e8[6] * r, e8[7] * r};
            f32x4* qp = reinterpret_cast<f32x4*>(qlds + nn * 256 + vl * 8);
            qp[0] = q0;
            qp[1] = q1;
        };
        qbuild(ap.x, 2 * j);
        qbuild(ap.y, 2 * j + 1);
    }

// ---- Phase C: M accumulation (patch gather x q from LDS) ----
#define GOFF(n) (((size_t)(b * VV + (a[n] ? a[n] - 1 : 0))) * 16 + j * 2)
#define CONS(n, P0, P1)                                                        \
    {                                                                          \
        const f32x4* qv =                                                      \
            reinterpret_cast<const f32x4*>(qlds + (n) * 256 + vl * 8);         \
        f32x4 q0 = qv[0];                                                      \
        f32x4 q1 = qv[1];                                                      \
        float p[8] = {P0.x, P0.y, P0.z, P0.w, P1.x, P1.y, P1.z, P1.w};         \
        _Pragma("unroll") for (int c = 0; c < 8; ++c) {                        \
            _Pragma("unroll") for (int k = 0; k < 4; ++k) {                    \
                acc[c][k] = fmaf(p[c], q0[k], acc[c][k]);                      \
                acc[c][k + 4] = fmaf(p[c], q1[k], acc[c][k + 4]);              \
            }                                                                  \
        }                                                                      \
    }
#define LOADPAIR(n, D0, D1, D2, D3)                                            \
    {                                                                          \
        size_t g0 = GOFF(n), g1 = GOFF((n) + 1);                               \
        D0 = x4[g0];                                                           \
        D1 = x4[g0 + 1];                                                       \
        D2 = x4[g1];                                                           \
        D3 = x4[g1 + 1];                                                       \
    }

    float4 A0, A1, A2, A3, B0, B1, B2, B3;
    LOADPAIR(0, A0, A1, A2, A3)  // in flight across the barrier
    __syncthreads();             // qlds visible to all

    float acc[8][KK];
#pragma unroll
    for (int c = 0; c < 8; ++c)
#pragma unroll
        for (int k = 0; k < KK; ++k) acc[c][k] = 0.f;

    LOADPAIR(2, B0, B1, B2, B3)
    CONS(0, A0, A1) CONS(1, A2, A3)
    LOADPAIR(4, A0, A1, A2, A3)
    CONS(2, B0, B1) CONS(3, B2, B3)
    LOADPAIR(6, B0, B1, B2, B3)
    CONS(4, A0, A1) CONS(5, A2, A3)
    LOADPAIR(8, A0, A1, A2, A3)
    CONS(6, B0, B1) CONS(7, B2, B3)
    LOADPAIR(10, B0, B1, B2, B3)
    CONS(8, A0, A1) CONS(9, A2, A3)
    LOADPAIR(12, A0, A1, A2, A3)
    CONS(10, B0, B1) CONS(11, B2, B3)
    LOADPAIR(14, B0, B1, B2, B3)
    CONS(12, A0, A1) CONS(13, A2, A3)
    CONS(14, B0, B1) CONS(15, B2, B3)

    __syncthreads();  // all q reads done -> safe to overwrite smem with M

    // ---- M -> bf16 LDS, conflict-free swizzle slot^((slot>>3)&7)^(row&7) ----
#pragma unroll
    for (int s = 0; s < 8; ++s) {
        bf16x8 w;
#pragma unroll
        for (int k = 0; k < KK; ++k) w[k] = f2b(acc[s][k]);
        int slot = j * 8 + s;
        int slot2 = slot ^ j ^ (vl & 7);  // ((slot>>3)&7) == j
        *reinterpret_cast<bf16x8*>(smem + vl * 1024 + slot2 * 16) = w;
    }
    __syncthreads();

    // ---- Phase 2: out[32x64] = M[32x512] @ Wb[512x64] via MFMA ----
    {
        int wid = t >> 6;   // wave 0..3
        int l = t & 63;
        int rt = wid >> 1;  // row tile (16 rows)
        int ch = wid & 1;   // col half (32 cols)
        int r = rt * 16 + (l & 15);

        f32x4 acc2[2];
        acc2[0] = (f32x4){0.f, 0.f, 0.f, 0.f};
        acc2[1] = (f32x4){0.f, 0.f, 0.f, 0.f};
        const bf16x8* WbV = reinterpret_cast<const bf16x8*>(Wb);

#pragma unroll
        for (int ks = 0; ks < 16; ++ks) {
            int ks4h = ks * 4 + (l >> 4);
            int slotA = ks4h ^ ((ks4h >> 3) & 7) ^ (r & 7);
            bf16x8 afrag = *reinterpret_cast<const bf16x8*>(
                smem + r * 1024 + slotA * 16);
#pragma unroll
            for (int ct = 0; ct < 2; ++ct) {
                bf16x8 bfrag = WbV[(ks * 4 + ch * 2 + ct) * 64 + l];
                acc2[ct] = __builtin_amdgcn_mfma_f32_16x16x32_bf16(
                    afrag, bfrag, acc2[ct], 0, 0, 0);
            }
        }

        // C/D layout: col = l&15, row = (l>>4)*4 + reg
#pragma unroll
        for (int ct = 0; ct < 2; ++ct) {
            int col = ch * 32 + ct * 16 + (l & 15);
#pragma unroll
            for (int jr = 0; jr < 4; ++jr) {
                int rowl = rt * 16 + (l >> 4) * 4 + jr;
                int vv = v0 + rowl;
                if (vv < VV) {
                    out[((size_t)b * VV + vv) * OO + col] =
                        acc2[ct][jr] * sInvd[rowl];
                }
            }
        }
    }
}

extern "C" void kernel_launch(void* const* d_in, const int* in_sizes, int n_in,
                              void* d_out, int out_size, void* d_ws,
                              size_t ws_size, hipStream_t stream) {
    const float* x = (const float*)d_in[0];  // (B,V,C) f32
    const float* u = (const float*)d_in[1];  // (C,K)   f32
    const float* W = (const float*)d_in[2];  // (C,K*O) f32
    const int* adj = (const int*)d_in[3];    // (V,NB)  i32
    float* out = (float*)d_out;              // (B,V,O) f32

    float* xu = (float*)d_ws;  // (B*V, K) f32 = 3.2 MB
    short* Wb = (short*)((char*)d_ws + (size_t)BB * VV * KK * sizeof(float));

    prep_kernel<<<XUB + WPB, 256, 0, stream>>>(x, u, xu, W, Wb);
    dim3 g((VV + TV - 1) / TV, BB);
    feast_fused<<<g, 256, 0, stream>>>(x, adj, xu, Wb, out);
}

// Round 10
// 166.649 us; speedup vs baseline: 2.6155x; 2.6155x over previous
//
#include <hip/hip_runtime.h>
#include <hip/hip_bf16.h>

// FeastNet fused: B=2, V=50000, NB=16, C=64, K=8, O=64
// out[b,v,o] = inv_deg[v] * sum_{c,k} M[c,k] * W[c,k,o]
//   M[c,k]   = sum_n patches[b,v,n,c] * q[b,v,n,k]
//   q        = softmax_k( xu[self] - xu[neighbor] ),  xu = x @ u
// v3 = v2 with __launch_bounds__(256,2): v2's (256,4) capped total regs at
// 128 (unified VGPR+AGPR file); MFMA acc took AGPRs leaving ~64 arch VGPRs,
// spilling Phase-C state (WRITE_SIZE 25MB->665MB, 3.5x regression). LDS
// (32.5KB) already caps residency at 4 blocks/CU, so (256,2) is free.

constexpr int BB = 2;
constexpr int VV = 50000;
#define NB 16
#define CC 64
#define KK 8
#define OO 64
#define TV 32  // vertices per workgroup

typedef __attribute__((ext_vector_type(8))) short bf16x8;  // 8 bf16 (4 VGPRs)
typedef __attribute__((ext_vector_type(4))) float f32x4;

static __device__ __forceinline__ short f2b(float f) {
    __hip_bfloat16 h = __float2bfloat16(f);  // RNE
    return *reinterpret_cast<short*>(&h);
}

// ---- K0 merged prep: xu (blocks [0,XUB)) + Wb prep (blocks [XUB, XUB+WPB)) ----
constexpr int XUB = (BB * VV * 2 + 255) / 256;  // 2 threads per row -> 782
constexpr int WPB = (CC * KK * OO) / 256;       // 128

__global__ void prep_kernel(const float* __restrict__ x,
                            const float* __restrict__ u,
                            float* __restrict__ xu,
                            const float* __restrict__ W,
                            short* __restrict__ Wb) {
    int blk = blockIdx.x;
    if (blk < XUB) {
        // xu[g,k] = sum_c x[g,c]*u[c,k]; thread = (row g, k-half)
        int t = blk * 256 + threadIdx.x;
        if (t >= BB * VV * 2) return;
        int g = t >> 1, half = t & 1;
        const float4* xr =
            reinterpret_cast<const float4*>(x) + (size_t)g * (CC / 4);
        const float4* u4 = reinterpret_cast<const float4*>(u);
        float a0 = 0.f, a1 = 0.f, a2 = 0.f, a3 = 0.f;
#pragma unroll
        for (int c4 = 0; c4 < CC / 4; ++c4) {
            float4 xv = xr[c4];
            float4 u0 = u4[(c4 * 4 + 0) * 2 + half];
            float4 u1 = u4[(c4 * 4 + 1) * 2 + half];
            float4 u2 = u4[(c4 * 4 + 2) * 2 + half];
            float4 u3 = u4[(c4 * 4 + 3) * 2 + half];
            a0 = fmaf(xv.x, u0.x, a0); a1 = fmaf(xv.x, u0.y, a1);
            a2 = fmaf(xv.x, u0.z, a2); a3 = fmaf(xv.x, u0.w, a3);
            a0 = fmaf(xv.y, u1.x, a0); a1 = fmaf(xv.y, u1.y, a1);
            a2 = fmaf(xv.y, u1.z, a2); a3 = fmaf(xv.y, u1.w, a3);
            a0 = fmaf(xv.z, u2.x, a0); a1 = fmaf(xv.z, u2.y, a1);
            a2 = fmaf(xv.z, u2.z, a2); a3 = fmaf(xv.z, u2.w, a3);
            a0 = fmaf(xv.w, u3.x, a0); a1 = fmaf(xv.w, u3.y, a1);
            a2 = fmaf(xv.w, u3.z, a2); a3 = fmaf(xv.w, u3.w, a3);
        }
        reinterpret_cast<float4*>(xu)[(size_t)g * 2 + half] =
            make_float4(a0, a1, a2, a3);
    } else {
        // W (C,K*O) f32 -> Wb bf16 in MFMA B-fragment order.
        // Wb[((ks*4+gct)*64+l)*8+e] = W[(ks*32+(l>>4)*8+e)*OO + gct*16+(l&15)]
        int dst = (blk - XUB) * 256 + threadIdx.x;
        int e = dst & 7;
        int l = (dst >> 3) & 63;
        int ctk = dst >> 9;
        int gct = ctk & 3;
        int ks = ctk >> 2;
        int ck = ks * 32 + (l >> 4) * 8 + e;
        int o = gct * 16 + (l & 15);
        Wb[dst] = f2b(W[ck * OO + o]);
    }
}

// ---------------- K2: fused q + M-build + MFMA contraction ----------------
__global__ __launch_bounds__(256, 2) void feast_fused(
    const float* __restrict__ x, const int* __restrict__ adj,
    const float* __restrict__ xu, const short* __restrict__ Wb,
    float* __restrict__ out) {
    // 32KB: first holds qlds fp32 [n][vl][k] (16KB), then reused as Mlds
    __shared__ char smem[TV * 1024];
    __shared__ float sInvd[TV];

    int t = threadIdx.x;
    int b = blockIdx.y;
    int v0 = blockIdx.x * TV;
    int vl = t >> 3;  // vertex local 0..31
    int j = t & 7;    // channel-octet 0..7
    int v = v0 + vl;
    if (v >= VV) v = VV - 1;

    float* qlds = reinterpret_cast<float*>(smem);

    // ---- adj row (kept in regs, compile-time indexed only) ----
    int a[NB];
    const int4* arow = reinterpret_cast<const int4*>(adj + (size_t)v * NB);
#pragma unroll
    for (int n4 = 0; n4 < 4; ++n4) {
        int4 t4 = arow[n4];
        a[n4 * 4 + 0] = t4.x;
        a[n4 * 4 + 1] = t4.y;
        a[n4 * 4 + 2] = t4.z;
        a[n4 * 4 + 3] = t4.w;
    }
    float deg = 0.f;
#pragma unroll
    for (int n = 0; n < NB; ++n) deg += (a[n] != 0) ? 1.f : 0.f;
    if (j == 0) sInvd[vl] = (deg > 0.f) ? (1.f / deg) : 0.f;

    const float4* xu4 = reinterpret_cast<const float4*>(xu);
    const float4* x4 = reinterpret_cast<const float4*>(x);

    // ---- Phase A: softmax q for this thread's 2 neighbors -> qlds ----
    {
        int gs = b * VV + v;
        float4 s0 = xu4[(size_t)gs * 2], s1 = xu4[(size_t)gs * 2 + 1];
        float xs[KK] = {s0.x, s0.y, s0.z, s0.w, s1.x, s1.y, s1.z, s1.w};
        int2 ap = *reinterpret_cast<const int2*>(adj + (size_t)v * NB + 2 * j);

        auto qbuild = [&](int an, int nn) {
            int g = b * VV + (an ? an - 1 : 0);
            float4 n0 = xu4[(size_t)g * 2], n1 = xu4[(size_t)g * 2 + 1];
            float l8[KK] = {xs[0] - n0.x, xs[1] - n0.y, xs[2] - n0.z,
                            xs[3] - n0.w, xs[4] - n1.x, xs[5] - n1.y,
                            xs[6] - n1.z, xs[7] - n1.w};
            float mx = l8[0];
#pragma unroll
            for (int k = 1; k < KK; ++k) mx = fmaxf(mx, l8[k]);
            float e8[KK];
            float sum = 0.f;
#pragma unroll
            for (int k = 0; k < KK; ++k) {
                e8[k] = __expf(l8[k] - mx);
                sum += e8[k];
            }
            float r = an ? (1.f / sum) : 0.f;
            f32x4 q0 = {e8[0] * r, e8[1] * r, e8[2] * r, e8[3] * r};
            f32x4 q1 = {e8[4] * r, e8[5] * r, e8[6] * r, e8[7] * r};
            f32x4* qp = reinterpret_cast<f32x4*>(qlds + nn * 256 + vl * 8);
            qp[0] = q0;
            qp[1] = q1;
        };
        qbuild(ap.x, 2 * j);
        qbuild(ap.y, 2 * j + 1);
    }

// ---- Phase C: M accumulation (patch gather x q from LDS) ----
#define GOFF(n) (((size_t)(b * VV + (a[n] ? a[n] - 1 : 0))) * 16 + j * 2)
#define CONS(n, P0, P1)                                                        \
    {                                                                          \
        const f32x4* qv =                                                      \
            reinterpret_cast<const f32x4*>(qlds + (n) * 256 + vl * 8);         \
        f32x4 q0 = qv[0];                                                      \
        f32x4 q1 = qv[1];                                                      \
        float p[8] = {P0.x, P0.y, P0.z, P0.w, P1.x, P1.y, P1.z, P1.w};         \
        _Pragma("unroll") for (int c = 0; c < 8; ++c) {                        \
            _Pragma("unroll") for (int k = 0; k < 4; ++k) {                    \
                acc[c][k] = fmaf(p[c], q0[k], acc[c][k]);                      \
                acc[c][k + 4] = fmaf(p[c], q1[k], acc[c][k + 4]);              \
            }                                                                  \
        }                                                                      \
    }
#define LOADPAIR(n, D0, D1, D2, D3)                                            \
    {                                                                          \
        size_t g0 = GOFF(n), g1 = GOFF((n) + 1);                               \
        D0 = x4[g0];                                                           \
        D1 = x4[g0 + 1];                                                       \
        D2 = x4[g1];                                                           \
        D3 = x4[g1 + 1];                                                       \
    }

    float4 A0, A1, A2, A3, B0, B1, B2, B3;
    LOADPAIR(0, A0, A1, A2, A3)  // in flight across the barrier
    __syncthreads();             // qlds visible to all

    float acc[8][KK];
#pragma unroll
    for (int c = 0; c < 8; ++c)
#pragma unroll
        for (int k = 0; k < KK; ++k) acc[c][k] = 0.f;

    LOADPAIR(2, B0, B1, B2, B3)
    CONS(0, A0, A1) CONS(1, A2, A3)
    LOADPAIR(4, A0, A1, A2, A3)
    CONS(2, B0, B1) CONS(3, B2, B3)
    LOADPAIR(6, B0, B1, B2, B3)
    CONS(4, A0, A1) CONS(5, A2, A3)
    LOADPAIR(8, A0, A1, A2, A3)
    CONS(6, B0, B1) CONS(7, B2, B3)
    LOADPAIR(10, B0, B1, B2, B3)
    CONS(8, A0, A1) CONS(9, A2, A3)
    LOADPAIR(12, A0, A1, A2, A3)
    CONS(10, B0, B1) CONS(11, B2, B3)
    LOADPAIR(14, B0, B1, B2, B3)
    CONS(12, A0, A1) CONS(13, A2, A3)
    CONS(14, B0, B1) CONS(15, B2, B3)

    __syncthreads();  // all q reads done -> safe to overwrite smem with M

    // ---- M -> bf16 LDS, conflict-free swizzle slot^((slot>>3)&7)^(row&7) ----
#pragma unroll
    for (int s = 0; s < 8; ++s) {
        bf16x8 w;
#pragma unroll
        for (int k = 0; k < KK; ++k) w[k] = f2b(acc[s][k]);
        int slot = j * 8 + s;
        int slot2 = slot ^ j ^ (vl & 7);  // ((slot>>3)&7) == j
        *reinterpret_cast<bf16x8*>(smem + vl * 1024 + slot2 * 16) = w;
    }
    __syncthreads();

    // ---- Phase 2: out[32x64] = M[32x512] @ Wb[512x64] via MFMA ----
    {
        int wid = t >> 6;   // wave 0..3
        int l = t & 63;
        int rt = wid >> 1;  // row tile (16 rows)
        int ch = wid & 1;   // col half (32 cols)
        int r = rt * 16 + (l & 15);

        f32x4 acc2[2];
        acc2[0] = (f32x4){0.f, 0.f, 0.f, 0.f};
        acc2[1] = (f32x4){0.f, 0.f, 0.f, 0.f};
        const bf16x8* WbV = reinterpret_cast<const bf16x8*>(Wb);

#pragma unroll
        for (int ks = 0; ks < 16; ++ks) {
            int ks4h = ks * 4 + (l >> 4);
            int slotA = ks4h ^ ((ks4h >> 3) & 7) ^ (r & 7);
            bf16x8 afrag = *reinterpret_cast<const bf16x8*>(
                smem + r * 1024 + slotA * 16);
#pragma unroll
            for (int ct = 0; ct < 2; ++ct) {
                bf16x8 bfrag = WbV[(ks * 4 + ch * 2 + ct) * 64 + l];
                acc2[ct] = __builtin_amdgcn_mfma_f32_16x16x32_bf16(
                    afrag, bfrag, acc2[ct], 0, 0, 0);
            }
        }

        // C/D layout: col = l&15, row = (l>>4)*4 + reg
#pragma unroll
        for (int ct = 0; ct < 2; ++ct) {
            int col = ch * 32 + ct * 16 + (l & 15);
#pragma unroll
            for (int jr = 0; jr < 4; ++jr) {
                int rowl = rt * 16 + (l >> 4) * 4 + jr;
                int vv = v0 + rowl;
                if (vv < VV) {
                    out[((size_t)b * VV + vv) * OO + col] =
                        acc2[ct][jr] * sInvd[rowl];
                }
            }
        }
    }
}

extern "C" void kernel_launch(void* const* d_in, const int* in_sizes, int n_in,
                              void* d_out, int out_size, void* d_ws,
                              size_t ws_size, hipStream_t stream) {
    const float* x = (const float*)d_in[0];  // (B,V,C) f32
    const float* u = (const float*)d_in[1];  // (C,K)   f32
    const float* W = (const float*)d_in[2];  // (C,K*O) f32
    const int* adj = (const int*)d_in[3];    // (V,NB)  i32
    float* out = (float*)d_out;              // (B,V,O) f32

    float* xu = (float*)d_ws;  // (B*V, K) f32 = 3.2 MB
    short* Wb = (short*)((char*)d_ws + (size_t)BB * VV * KK * sizeof(float));

    prep_kernel<<<XUB + WPB, 256, 0, stream>>>(x, u, xu, W, Wb);
    dim3 g((VV + TV - 1) / TV, BB);
    feast_fused<<<g, 256, 0, stream>>>(x, adj, xu, Wb, out);
}

// Round 12
// 166.080 us; speedup vs baseline: 2.6245x; 1.0034x over previous
//
#include <hip/hip_runtime.h>
#include <hip/hip_bf16.h>

// FeastNet fused: B=2, V=50000, NB=16, C=64, K=8, O=64
// out[b,v,o] = inv_deg[v] * sum_{c,k} M[c,k] * W[c,k,o]
//   M[c,k]   = sum_n patches[b,v,n,c] * q[b,v,n,k]
//   q        = softmax_k( xu[self] - xu[neighbor] ),  xu = x @ u
// v4: TV=16, 16 threads/vertex (1 neighbor softmax each, acc[4][8]),
//     LDS 16.5KB (5+ blocks/CU), depth-6 rolling gather prefetch.
//     v3 diagnosis: gather-latency-bound, 19% occupancy, VALU 25%.

constexpr int BB = 2;
constexpr int VV = 50000;
#define NB 16
#define CC 64
#define KK 8
#define OO 64
#define TV 16  // vertices per workgroup (256 threads, 16 threads/vertex)

typedef __attribute__((ext_vector_type(8))) short bf16x8;  // 8 bf16 (4 VGPRs)
typedef __attribute__((ext_vector_type(4))) float f32x4;

static __device__ __forceinline__ short f2b(float f) {
    __hip_bfloat16 h = __float2bfloat16(f);  // RNE
    return *reinterpret_cast<short*>(&h);
}

// ---- K0 merged prep: xu (blocks [0,XUB)) + Wb prep (blocks [XUB, XUB+WPB)) ----
constexpr int XUB = (BB * VV * 2 + 255) / 256;  // 2 threads per row -> 782
constexpr int WPB = (CC * KK * OO) / 256;       // 128

__global__ void prep_kernel(const float* __restrict__ x,
                            const float* __restrict__ u,
                            float* __restrict__ xu,
                            const float* __restrict__ W,
                            short* __restrict__ Wb) {
    int blk = blockIdx.x;
    if (blk < XUB) {
        // xu[g,k] = sum_c x[g,c]*u[c,k]; thread = (row g, k-half)
        int t = blk * 256 + threadIdx.x;
        if (t >= BB * VV * 2) return;
        int g = t >> 1, half = t & 1;
        const float4* xr =
            reinterpret_cast<const float4*>(x) + (size_t)g * (CC / 4);
        const float4* u4 = reinterpret_cast<const float4*>(u);
        float a0 = 0.f, a1 = 0.f, a2 = 0.f, a3 = 0.f;
#pragma unroll
        for (int c4 = 0; c4 < CC / 4; ++c4) {
            float4 xv = xr[c4];
            float4 u0 = u4[(c4 * 4 + 0) * 2 + half];
            float4 u1 = u4[(c4 * 4 + 1) * 2 + half];
            float4 u2 = u4[(c4 * 4 + 2) * 2 + half];
            float4 u3 = u4[(c4 * 4 + 3) * 2 + half];
            a0 = fmaf(xv.x, u0.x, a0); a1 = fmaf(xv.x, u0.y, a1);
            a2 = fmaf(xv.x, u0.z, a2); a3 = fmaf(xv.x, u0.w, a3);
            a0 = fmaf(xv.y, u1.x, a0); a1 = fmaf(xv.y, u1.y, a1);
            a2 = fmaf(xv.y, u1.z, a2); a3 = fmaf(xv.y, u1.w, a3);
            a0 = fmaf(xv.z, u2.x, a0); a1 = fmaf(xv.z, u2.y, a1);
            a2 = fmaf(xv.z, u2.z, a2); a3 = fmaf(xv.z, u2.w, a3);
            a0 = fmaf(xv.w, u3.x, a0); a1 = fmaf(xv.w, u3.y, a1);
            a2 = fmaf(xv.w, u3.z, a2); a3 = fmaf(xv.w, u3.w, a3);
        }
        reinterpret_cast<float4*>(xu)[(size_t)g * 2 + half] =
            make_float4(a0, a1, a2, a3);
    } else {
        // W (C,K*O) f32 -> Wb bf16 in MFMA B-fragment order.
        // Wb[((ks*4+gct)*64+l)*8+e] = W[(ks*32+(l>>4)*8+e)*OO + gct*16+(l&15)]
        int dst = (blk - XUB) * 256 + threadIdx.x;
        int e = dst & 7;
        int l = (dst >> 3) & 63;
        int ctk = dst >> 9;
        int gct = ctk & 3;
        int ks = ctk >> 2;
        int ck = ks * 32 + (l >> 4) * 8 + e;
        int o = gct * 16 + (l & 15);
        Wb[dst] = f2b(W[ck * OO + o]);
    }
}

// ---------------- K2: fused q + M-build + MFMA contraction ----------------
__global__ __launch_bounds__(256, 4) void feast_fused(
    const float* __restrict__ x, const int* __restrict__ adj,
    const float* __restrict__ xu, const short* __restrict__ Wb,
    float* __restrict__ out) {
    // 16KB: first 8KB holds qlds fp32 [n=16][vl=16][k=8]; then all 16KB
    // reused as M bf16 [16][512] (row = 1024B = 64 16B-slots, swizzled).
    __shared__ char smem[TV * 1024];
    __shared__ float sInvd[TV];

    int t = threadIdx.x;
    int b = blockIdx.y;
    int v0 = blockIdx.x * TV;
    int vl = t >> 4;  // vertex local 0..15
    int jj = t & 15;  // Phase A: neighbor idx; Phase C: channel-quad idx
    int v = v0 + vl;  // VV % TV == 0: always valid

    float* qlds = reinterpret_cast<float*>(smem);
    const float4* xu4 = reinterpret_cast<const float4*>(xu);
    const float4* x4 = reinterpret_cast<const float4*>(x);

    // ---- adj row (regs, compile-time indexed only) ----
    int a[NB];
    const int4* arow = reinterpret_cast<const int4*>(adj + (size_t)v * NB);
#pragma unroll
    for (int n4 = 0; n4 < 4; ++n4) {
        int4 t4 = arow[n4];
        a[n4 * 4 + 0] = t4.x;
        a[n4 * 4 + 1] = t4.y;
        a[n4 * 4 + 2] = t4.z;
        a[n4 * 4 + 3] = t4.w;
    }
    float deg = 0.f;
#pragma unroll
    for (int n = 0; n < NB; ++n) deg += (a[n] != 0) ? 1.f : 0.f;
    if (jj == 0) sInvd[vl] = (deg > 0.f) ? (1.f / deg) : 0.f;

    // ---- Phase A: softmax q for neighbor jj of vertex vl -> qlds ----
    {
        int gs = b * VV + v;
        float4 s0 = xu4[(size_t)gs * 2], s1 = xu4[(size_t)gs * 2 + 1];
        int an = adj[(size_t)v * NB + jj];  // direct load (no dyn reg index)
        int g = b * VV + (an ? an - 1 : 0);
        float4 n0 = xu4[(size_t)g * 2], n1 = xu4[(size_t)g * 2 + 1];
        float l8[KK] = {s0.x - n0.x, s0.y - n0.y, s0.z - n0.z, s0.w - n0.w,
                        s1.x - n1.x, s1.y - n1.y, s1.z - n1.z, s1.w - n1.w};
        float mx = l8[0];
#pragma unroll
        for (int k = 1; k < KK; ++k) mx = fmaxf(mx, l8[k]);
        float e8[KK];
        float sum = 0.f;
#pragma unroll
        for (int k = 0; k < KK; ++k) {
            e8[k] = __expf(l8[k] - mx);
            sum += e8[k];
        }
        float r = an ? (1.f / sum) : 0.f;
        f32x4* qp = reinterpret_cast<f32x4*>(qlds + jj * 128 + vl * 8);
        qp[0] = (f32x4){e8[0] * r, e8[1] * r, e8[2] * r, e8[3] * r};
        qp[1] = (f32x4){e8[4] * r, e8[5] * r, e8[6] * r, e8[7] * r};
    }

// ---- Phase C: acc[c=4][k=8] over 16 neighbors, depth-6 prefetch ----
#define GOFFN(n) (((size_t)(b * VV + (a[n] ? a[n] - 1 : 0))) * 16 + jj)
#define CONS(n, P)                                                             \
    {                                                                          \
        const f32x4* qv =                                                      \
            reinterpret_cast<const f32x4*>(qlds + (n) * 128 + vl * 8);         \
        f32x4 q0 = qv[0];                                                      \
        f32x4 q1 = qv[1];                                                      \
        float p[4] = {P.x, P.y, P.z, P.w};                                     \
        _Pragma("unroll") for (int c = 0; c < 4; ++c) {                        \
            _Pragma("unroll") for (int k = 0; k < 4; ++k) {                    \
                acc[c][k] = fmaf(p[c], q0[k], acc[c][k]);                      \
                acc[c][k + 4] = fmaf(p[c], q1[k], acc[c][k + 4]);              \
            }                                                                  \
        }                                                                      \
    }

    float4 P0, P1, P2, P3, P4, P5;
    P0 = x4[GOFFN(0)];
    P1 = x4[GOFFN(1)];
    P2 = x4[GOFFN(2)];
    P3 = x4[GOFFN(3)];
    P4 = x4[GOFFN(4)];
    P5 = x4[GOFFN(5)];
    __syncthreads();  // qlds visible; first 6 gathers in flight across barrier

    float acc[4][KK];
#pragma unroll
    for (int c = 0; c < 4; ++c)
#pragma unroll
        for (int k = 0; k < KK; ++k) acc[c][k] = 0.f;

    CONS(0, P0) P0 = x4[GOFFN(6)];
    CONS(1, P1) P1 = x4[GOFFN(7)];
    CONS(2, P2) P2 = x4[GOFFN(8)];
    CONS(3, P3) P3 = x4[GOFFN(9)];
    CONS(4, P4) P4 = x4[GOFFN(10)];
    CONS(5, P5) P5 = x4[GOFFN(11)];
    CONS(6, P0) P0 = x4[GOFFN(12)];
    CONS(7, P1) P1 = x4[GOFFN(13)];
    CONS(8, P2) P2 = x4[GOFFN(14)];
    CONS(9, P3) P3 = x4[GOFFN(15)];
    CONS(10, P4)
    CONS(11, P5)
    CONS(12, P0)
    CONS(13, P1)
    CONS(14, P2)
    CONS(15, P3)

    __syncthreads();  // all q reads done -> safe to overwrite smem with M

    // ---- M -> bf16 LDS; slot = channel c = jj*4+s (8 k-values per slot),
    //      swizzle slot2 = slot ^ ((slot>>3)&7) ^ (row&7) (same as read side)
#pragma unroll
    for (int s = 0; s < 4; ++s) {
        bf16x8 w;
#pragma unroll
        for (int k = 0; k < KK; ++k) w[k] = f2b(acc[s][k]);
        int slot = jj * 4 + s;
        int slot2 = slot ^ ((slot >> 3) & 7) ^ (vl & 7);
        *reinterpret_cast<bf16x8*>(smem + vl * 1024 + slot2 * 16) = w;
    }
    __syncthreads();

    // ---- Phase 2: out[16x64] = M[16x512] @ Wb[512x64] via MFMA ----
    {
        int wid = t >> 6;  // wave 0..3 = col tile (16 cols each)
        int l = t & 63;
        int r = l & 15;  // A-frag row

        f32x4 acc2 = (f32x4){0.f, 0.f, 0.f, 0.f};
        const bf16x8* WbV = reinterpret_cast<const bf16x8*>(Wb);

#pragma unroll
        for (int ks = 0; ks < 16; ++ks) {
            int ks4h = ks * 4 + (l >> 4);
            int slotA = ks4h ^ ((ks4h >> 3) & 7) ^ (r & 7);
            bf16x8 afrag = *reinterpret_cast<const bf16x8*>(
                smem + r * 1024 + slotA * 16);
            bf16x8 bfrag = WbV[(ks * 4 + wid) * 64 + l];
            acc2 = __builtin_amdgcn_mfma_f32_16x16x32_bf16(afrag, bfrag, acc2,
                                                           0, 0, 0);
        }

        // C/D layout: col = l&15, row = (l>>4)*4 + reg
        int col = wid * 16 + (l & 15);
#pragma unroll
        for (int jr = 0; jr < 4; ++jr) {
            int rowl = (l >> 4) * 4 + jr;
            out[((size_t)b * VV + v0 + rowl) * OO + col] =
                acc2[jr] * sInvd[rowl];
        }
    }
}

extern "C" void kernel_launch(void* const* d_in, const int* in_sizes, int n_in,
                              void* d_out, int out_size, void* d_ws,
                              size_t ws_size, hipStream_t stream) {
    const float* x = (const float*)d_in[0];  // (B,V,C) f32
    const float* u = (const float*)d_in[1];  // (C,K)   f32
    const float* W = (const float*)d_in[2];  // (C,K*O) f32
    const int* adj = (const int*)d_in[3];    // (V,NB)  i32
    float* out = (float*)d_out;              // (B,V,O) f32

    float* xu = (float*)d_ws;  // (B*V, K) f32 = 3.2 MB
    short* Wb = (short*)((char*)d_ws + (size_t)BB * VV * KK * sizeof(float));

    prep_kernel<<<XUB + WPB, 256, 0, stream>>>(x, u, xu, W, Wb);
    dim3 g(VV / TV, BB);
    feast_fused<<<g, 256, 0, stream>>>(x, adj, xu, Wb, out);
}

// Round 13
// 153.897 us; speedup vs baseline: 2.8322x; 1.0792x over previous
//
#include <hip/hip_runtime.h>
#include <hip/hip_bf16.h>

// FeastNet fused: B=2, V=50000, NB=16, C=64, K=8, O=64
// out[b,v,o] = inv_deg[v] * sum_{c,k} M[c,k] * W[c,k,o]
//   M[c,k]   = sum_n patches[b,v,n,c] * q[b,v,n,k]
//   q        = softmax_k( xu[self] - xu[neighbor] ),  xu = x @ u
// v5 = v4 with __launch_bounds__(256,3): v4's (256,4)=128-reg budget still
// spilled ~7 dwords/thread (VGPR=64 signature, WRITE_SIZE 25->68.7MB).
// Live set is ~140 (acc 32 + 6 prefetch f4 + 16 addrs + temps); (256,3)=170
// regs -> 3 waves/SIMD = same 38% occupancy as measured, but zero spill.

constexpr int BB = 2;
constexpr int VV = 50000;
#define NB 16
#define CC 64
#define KK 8
#define OO 64
#define TV 16  // vertices per workgroup (256 threads, 16 threads/vertex)

typedef __attribute__((ext_vector_type(8))) short bf16x8;  // 8 bf16 (4 VGPRs)
typedef __attribute__((ext_vector_type(4))) float f32x4;

static __device__ __forceinline__ short f2b(float f) {
    __hip_bfloat16 h = __float2bfloat16(f);  // RNE
    return *reinterpret_cast<short*>(&h);
}

// ---- K0 merged prep: xu (blocks [0,XUB)) + Wb prep (blocks [XUB, XUB+WPB)) ----
constexpr int XUB = (BB * VV * 2 + 255) / 256;  // 2 threads per row -> 782
constexpr int WPB = (CC * KK * OO) / 256;       // 128

__global__ void prep_kernel(const float* __restrict__ x,
                            const float* __restrict__ u,
                            float* __restrict__ xu,
                            const float* __restrict__ W,
                            short* __restrict__ Wb) {
    int blk = blockIdx.x;
    if (blk < XUB) {
        // xu[g,k] = sum_c x[g,c]*u[c,k]; thread = (row g, k-half)
        int t = blk * 256 + threadIdx.x;
        if (t >= BB * VV * 2) return;
        int g = t >> 1, half = t & 1;
        const float4* xr =
            reinterpret_cast<const float4*>(x) + (size_t)g * (CC / 4);
        const float4* u4 = reinterpret_cast<const float4*>(u);
        float a0 = 0.f, a1 = 0.f, a2 = 0.f, a3 = 0.f;
#pragma unroll
        for (int c4 = 0; c4 < CC / 4; ++c4) {
            float4 xv = xr[c4];
            float4 u0 = u4[(c4 * 4 + 0) * 2 + half];
            float4 u1 = u4[(c4 * 4 + 1) * 2 + half];
            float4 u2 = u4[(c4 * 4 + 2) * 2 + half];
            float4 u3 = u4[(c4 * 4 + 3) * 2 + half];
            a0 = fmaf(xv.x, u0.x, a0); a1 = fmaf(xv.x, u0.y, a1);
            a2 = fmaf(xv.x, u0.z, a2); a3 = fmaf(xv.x, u0.w, a3);
            a0 = fmaf(xv.y, u1.x, a0); a1 = fmaf(xv.y, u1.y, a1);
            a2 = fmaf(xv.y, u1.z, a2); a3 = fmaf(xv.y, u1.w, a3);
            a0 = fmaf(xv.z, u2.x, a0); a1 = fmaf(xv.z, u2.y, a1);
            a2 = fmaf(xv.z, u2.z, a2); a3 = fmaf(xv.z, u2.w, a3);
            a0 = fmaf(xv.w, u3.x, a0); a1 = fmaf(xv.w, u3.y, a1);
            a2 = fmaf(xv.w, u3.z, a2); a3 = fmaf(xv.w, u3.w, a3);
        }
        reinterpret_cast<float4*>(xu)[(size_t)g * 2 + half] =
            make_float4(a0, a1, a2, a3);
    } else {
        // W (C,K*O) f32 -> Wb bf16 in MFMA B-fragment order.
        // Wb[((ks*4+gct)*64+l)*8+e] = W[(ks*32+(l>>4)*8+e)*OO + gct*16+(l&15)]
        int dst = (blk - XUB) * 256 + threadIdx.x;
        int e = dst & 7;
        int l = (dst >> 3) & 63;
        int ctk = dst >> 9;
        int gct = ctk & 3;
        int ks = ctk >> 2;
        int ck = ks * 32 + (l >> 4) * 8 + e;
        int o = gct * 16 + (l & 15);
        Wb[dst] = f2b(W[ck * OO + o]);
    }
}

// ---------------- K2: fused q + M-build + MFMA contraction ----------------
__global__ __launch_bounds__(256, 3) void feast_fused(
    const float* __restrict__ x, const int* __restrict__ adj,
    const float* __restrict__ xu, const short* __restrict__ Wb,
    float* __restrict__ out) {
    // 16KB: first 8KB holds qlds fp32 [n=16][vl=16][k=8]; then all 16KB
    // reused as M bf16 [16][512] (row = 1024B = 64 16B-slots, swizzled).
    __shared__ char smem[TV * 1024];
    __shared__ float sInvd[TV];

    int t = threadIdx.x;
    int b = blockIdx.y;
    int v0 = blockIdx.x * TV;
    int vl = t >> 4;  // vertex local 0..15
    int jj = t & 15;  // Phase A: neighbor idx; Phase C: channel-quad idx
    int v = v0 + vl;  // VV % TV == 0: always valid

    float* qlds = reinterpret_cast<float*>(smem);
    const float4* xu4 = reinterpret_cast<const float4*>(xu);
    const float4* x4 = reinterpret_cast<const float4*>(x);

    // ---- adj row (regs, compile-time indexed only) ----
    int a[NB];
    const int4* arow = reinterpret_cast<const int4*>(adj + (size_t)v * NB);
#pragma unroll
    for (int n4 = 0; n4 < 4; ++n4) {
        int4 t4 = arow[n4];
        a[n4 * 4 + 0] = t4.x;
        a[n4 * 4 + 1] = t4.y;
        a[n4 * 4 + 2] = t4.z;
        a[n4 * 4 + 3] = t4.w;
    }
    float deg = 0.f;
#pragma unroll
    for (int n = 0; n < NB; ++n) deg += (a[n] != 0) ? 1.f : 0.f;
    if (jj == 0) sInvd[vl] = (deg > 0.f) ? (1.f / deg) : 0.f;

    // ---- Phase A: softmax q for neighbor jj of vertex vl -> qlds ----
    {
        int gs = b * VV + v;
        float4 s0 = xu4[(size_t)gs * 2], s1 = xu4[(size_t)gs * 2 + 1];
        int an = adj[(size_t)v * NB + jj];  // direct load (no dyn reg index)
        int g = b * VV + (an ? an - 1 : 0);
        float4 n0 = xu4[(size_t)g * 2], n1 = xu4[(size_t)g * 2 + 1];
        float l8[KK] = {s0.x - n0.x, s0.y - n0.y, s0.z - n0.z, s0.w - n0.w,
                        s1.x - n1.x, s1.y - n1.y, s1.z - n1.z, s1.w - n1.w};
        float mx = l8[0];
#pragma unroll
        for (int k = 1; k < KK; ++k) mx = fmaxf(mx, l8[k]);
        float e8[KK];
        float sum = 0.f;
#pragma unroll
        for (int k = 0; k < KK; ++k) {
            e8[k] = __expf(l8[k] - mx);
            sum += e8[k];
        }
        float r = an ? (1.f / sum) : 0.f;
        f32x4* qp = reinterpret_cast<f32x4*>(qlds + jj * 128 + vl * 8);
        qp[0] = (f32x4){e8[0] * r, e8[1] * r, e8[2] * r, e8[3] * r};
        qp[1] = (f32x4){e8[4] * r, e8[5] * r, e8[6] * r, e8[7] * r};
    }

// ---- Phase C: acc[c=4][k=8] over 16 neighbors, depth-6 prefetch ----
#define GOFFN(n) (((size_t)(b * VV + (a[n] ? a[n] - 1 : 0))) * 16 + jj)
#define CONS(n, P)                                                             \
    {                                                                          \
        const f32x4* qv =                                                      \
            reinterpret_cast<const f32x4*>(qlds + (n) * 128 + vl * 8);         \
        f32x4 q0 = qv[0];                                                      \
        f32x4 q1 = qv[1];                                                      \
        float p[4] = {P.x, P.y, P.z, P.w};                                     \
        _Pragma("unroll") for (int c = 0; c < 4; ++c) {                        \
            _Pragma("unroll") for (int k = 0; k < 4; ++k) {                    \
                acc[c][k] = fmaf(p[c], q0[k], acc[c][k]);                      \
                acc[c][k + 4] = fmaf(p[c], q1[k], acc[c][k + 4]);              \
            }                                                                  \
        }                                                                      \
    }

    float4 P0, P1, P2, P3, P4, P5;
    P0 = x4[GOFFN(0)];
    P1 = x4[GOFFN(1)];
    P2 = x4[GOFFN(2)];
    P3 = x4[GOFFN(3)];
    P4 = x4[GOFFN(4)];
    P5 = x4[GOFFN(5)];
    __syncthreads();  // qlds visible; first 6 gathers in flight across barrier

    float acc[4][KK];
#pragma unroll
    for (int c = 0; c < 4; ++c)
#pragma unroll
        for (int k = 0; k < KK; ++k) acc[c][k] = 0.f;

    CONS(0, P0) P0 = x4[GOFFN(6)];
    CONS(1, P1) P1 = x4[GOFFN(7)];
    CONS(2, P2) P2 = x4[GOFFN(8)];
    CONS(3, P3) P3 = x4[GOFFN(9)];
    CONS(4, P4) P4 = x4[GOFFN(10)];
    CONS(5, P5) P5 = x4[GOFFN(11)];
    CONS(6, P0) P0 = x4[GOFFN(12)];
    CONS(7, P1) P1 = x4[GOFFN(13)];
    CONS(8, P2) P2 = x4[GOFFN(14)];
    CONS(9, P3) P3 = x4[GOFFN(15)];
    CONS(10, P4)
    CONS(11, P5)
    CONS(12, P0)
    CONS(13, P1)
    CONS(14, P2)
    CONS(15, P3)

    __syncthreads();  // all q reads done -> safe to overwrite smem with M

    // ---- M -> bf16 LDS; slot = channel c = jj*4+s (8 k-values per slot),
    //      swizzle slot2 = slot ^ ((slot>>3)&7) ^ (row&7) (same as read side)
#pragma unroll
    for (int s = 0; s < 4; ++s) {
        bf16x8 w;
#pragma unroll
        for (int k = 0; k < KK; ++k) w[k] = f2b(acc[s][k]);
        int slot = jj * 4 + s;
        int slot2 = slot ^ ((slot >> 3) & 7) ^ (vl & 7);
        *reinterpret_cast<bf16x8*>(smem + vl * 1024 + slot2 * 16) = w;
    }
    __syncthreads();

    // ---- Phase 2: out[16x64] = M[16x512] @ Wb[512x64] via MFMA ----
    {
        int wid = t >> 6;  // wave 0..3 = col tile (16 cols each)
        int l = t & 63;
        int r = l & 15;  // A-frag row

        f32x4 acc2 = (f32x4){0.f, 0.f, 0.f, 0.f};
        const bf16x8* WbV = reinterpret_cast<const bf16x8*>(Wb);

#pragma unroll
        for (int ks = 0; ks < 16; ++ks) {
            int ks4h = ks * 4 + (l >> 4);
            int slotA = ks4h ^ ((ks4h >> 3) & 7) ^ (r & 7);
            bf16x8 afrag = *reinterpret_cast<const bf16x8*>(
                smem + r * 1024 + slotA * 16);
            bf16x8 bfrag = WbV[(ks * 4 + wid) * 64 + l];
            acc2 = __builtin_amdgcn_mfma_f32_16x16x32_bf16(afrag, bfrag, acc2,
                                                           0, 0, 0);
        }

        // C/D layout: col = l&15, row = (l>>4)*4 + reg
        int col = wid * 16 + (l & 15);
#pragma unroll
        for (int jr = 0; jr < 4; ++jr) {
            int rowl = (l >> 4) * 4 + jr;
            out[((size_t)b * VV + v0 + rowl) * OO + col] =
                acc2[jr] * sInvd[rowl];
        }
    }
}

extern "C" void kernel_launch(void* const* d_in, const int* in_sizes, int n_in,
                              void* d_out, int out_size, void* d_ws,
                              size_t ws_size, hipStream_t stream) {
    const float* x = (const float*)d_in[0];  // (B,V,C) f32
    const float* u = (const float*)d_in[1];  // (C,K)   f32
    const float* W = (const float*)d_in[2];  // (C,K*O) f32
    const int* adj = (const int*)d_in[3];    // (V,NB)  i32
    float* out = (float*)d_out;              // (B,V,O) f32

    float* xu = (float*)d_ws;  // (B*V, K) f32 = 3.2 MB
    short* Wb = (short*)((char*)d_ws + (size_t)BB * VV * KK * sizeof(float));

    prep_kernel<<<XUB + WPB, 256, 0, stream>>>(x, u, xu, W, Wb);
    dim3 g(VV / TV, BB);
    feast_fused<<<g, 256, 0, stream>>>(x, adj, xu, Wb, out);
}